// Round 7
// baseline (105.732 us; speedup 1.0000x reference)
//
#include <hip/hip_runtime.h>
#include <stdint.h>

#define B_    4096
#define T_    48
#define D_    35
#define KROW  168           // A-row stride (elems); MFMA reads k 0..159; 136..167 zero
#define TROW  16            // MFMA tile rows (fixed)
#define BT    8             // real batch rows per block (tile rows 8..15 zero)
#define ROWEL (T_ * D_)     // 1680
#define L2E   1.44269504f

typedef float f32x4 __attribute__((ext_vector_type(4)));
typedef short bf16x8 __attribute__((ext_vector_type(8)));

__device__ __forceinline__ uint32_t fbits(float x) { union { float f; uint32_t u; } v; v.f = x; return v.u; }
__device__ __forceinline__ float bitsf(uint32_t u) { union { uint32_t u; float f; } v; v.u = u; return v.f; }
__device__ __forceinline__ float bf2f(unsigned short b) { return bitsf(((uint32_t)b) << 16); }
__device__ __forceinline__ unsigned short f2bf_rne(float x) {
    uint32_t u = fbits(x);
    return (unsigned short)((u + 0x7fffu + ((u >> 16) & 1u)) >> 16);
}
__device__ __forceinline__ float rcp_(float x)  { return __builtin_amdgcn_rcpf(x); }
__device__ __forceinline__ float exp2_(float x) { return __builtin_amdgcn_exp2f(x); }

// K-axis layout (A tile and weight fragments):
//   k 0..34 = x_c -> W_ih[:,0:35] ; k 35..69 = m -> W_ih[:,35:70]
//   k 70..71 = 0  ; k 72..135 = h -> W_hh   ; k 136..159 = 0
// Chunk schedule: kk2..kk4 (m-tail+h) and P1 issue PRE-bar1 (m pre-written one
// step ahead); kk0, kk1 (x_c-dependent) issue POST-bar1.

__global__ __launch_bounds__(256, 2)
void brits_main(const float* __restrict__ x_t, const float* __restrict__ masks,
                const float* __restrict__ W_ih, const float* __restrict__ W_hh,
                const float* __restrict__ b_ih, const float* __restrict__ b_hh,
                const float* __restrict__ W_reg, const float* __restrict__ b_reg,
                const float* __restrict__ W_out, const float* __restrict__ b_out,
                float* __restrict__ ws, float* __restrict__ out)
{
    __shared__ __align__(16) unsigned short Abuf[2][TROW * KROW];  // 10752 B
    __shared__ __align__(16) unsigned short stash[BT * ROWEL];     // 26880 B: bf16(m*x) -> bf16(x_c)
    __shared__ unsigned long long mbits[BT * T_];                  //  3072 B
    __shared__ float lsum[T_ * 3 * 32];                            // 18432 B (waves 0..2, lanes 0..31)
    __shared__ float wout[65];

    const int tid    = threadIdx.x;
    const int lane   = tid & 63;
    const int w      = tid >> 6;      // wave 0..3
    const int g      = lane >> 4;     // k-subgroup / C row-group
    const int cc     = lane & 15;
    const int batch0 = blockIdx.x * BT;
    const int u      = w * 16 + cc;   // gate unit (all waves) / x_hat col (w<3)

    // ---- staging ----
    for (int i = tid; i < TROW * KROW; i += 256) ((uint32_t*)Abuf)[i] = 0;  // both buffers
    if (tid < 65) wout[tid] = (tid < 64) ? W_out[tid] : b_out[0];

    for (int i = tid; i < BT * (ROWEL / 8); i += 256) {
        const int r = i / 210;
        const int o = (i - r * 210) * 8;
        const float* xp = x_t   + (size_t)(batch0 + r) * ROWEL + o;
        const float* mp = masks + (size_t)(batch0 + r) * ROWEL + o;
        float xv[8], mv[8];
        *(float4*)&xv[0] = *(const float4*)xp; *(float4*)&xv[4] = *(const float4*)(xp + 4);
        *(float4*)&mv[0] = *(const float4*)mp; *(float4*)&mv[4] = *(const float4*)(mp + 4);
        unsigned short pk[8];
        #pragma unroll
        for (int k = 0; k < 8; ++k) pk[k] = f2bf_rne(mv[k] * xv[k]);
        *(uint4*)&stash[r * ROWEL + o] = *(const uint4*)pk;
    }
    for (int p = tid; p < BT * T_; p += 256) {
        const int r = p / T_, t = p - r * T_;
        const float* mp = masks + (size_t)(batch0 + r) * ROWEL + t * D_;
        unsigned long long bits = 0;
        for (int d = 0; d < D_; ++d) bits |= (unsigned long long)(mp[d] != 0.0f) << d;
        mbits[p] = bits;
    }

    // ---- weights -> registers ----
    bf16x8 Wf[4][5];
    #pragma unroll
    for (int G = 0; G < 4; ++G) {
        const int n = G * 64 + u;
        #pragma unroll
        for (int kk = 0; kk < 5; ++kk) {
            bf16x8 v;
            #pragma unroll
            for (int i = 0; i < 8; ++i) {
                const int k = kk * 32 + 8 * g + i;
                float f = 0.f;
                if (k < 70)                  f = W_ih[n * 70 + k];
                else if (k >= 72 && k < 136) f = W_hh[n * 64 + (k - 72)];
                v[i] = (short)f2bf_rne(f);
            }
            Wf[G][kk] = v;
        }
    }
    bf16x8 Wr0, Wr1;   // x_hat weights for col u (w<3)
    {
        const bool ok = (w < 3) && (u < 35);
        #pragma unroll
        for (int i = 0; i < 8; ++i) {
            Wr0[i] = (short)(ok ? f2bf_rne(W_reg[u * 64 + 8 * g + i])      : 0);
            Wr1[i] = (short)(ok ? f2bf_rne(W_reg[u * 64 + 32 + 8 * g + i]) : 0);
        }
    }
    const float brg = ((w < 3) && (u < 35)) ? b_reg[u] : 0.f;
    const float bIs = -(b_ih[u]       + b_hh[u])       * L2E;
    const float bFs = -(b_ih[64 + u]  + b_hh[64 + u])  * L2E;
    const float bGs = -(b_ih[128 + u] + b_hh[128 + u]) * 2.f * L2E;
    const float bOs = -(b_ih[192 + u] + b_hh[192 + u]) * L2E;
    __syncthreads();   // stash + mbits ready

    // ---- per-lane mask bitmaps over t, first x*m prefetch, m(0) pre-write ----
    const bool pl = (w < 3) && (u < 35) && (g < 2);   // epilogue lanes: rows 0..7
    unsigned long long PM[4] = {0, 0, 0, 0};
    uint32_t xmr[4] = {0, 0, 0, 0};
    if (pl) {
        #pragma unroll
        for (int j = 0; j < 4; ++j) {
            const int row = 4 * g + j;
            unsigned long long pm = 0;
            for (int t = 0; t < T_; ++t)
                pm |= ((mbits[row * T_ + t] >> u) & 1ull) << t;
            PM[j] = pm;
            xmr[j] = stash[row * ROWEL + u];                       // t=0
            Abuf[0][row * KROW + 35 + u] = (pm & 1ull) ? (unsigned short)0x3F80 : (unsigned short)0;
        }
    }
    __syncthreads();   // m(0) visible

    float c_reg[4] = {0.f, 0.f, 0.f, 0.f};

    for (int t = 0; t < T_; ++t) {
        unsigned short* A  = Abuf[t & 1];
        unsigned short* An = Abuf[(t + 1) & 1];

        // ---- pre-bar1: everything that depends only on h(t-1) and m(t) ----
        bf16x8 ah0 = *(const bf16x8*)&A[cc * KROW + 72  + 8 * g];
        bf16x8 ah1 = *(const bf16x8*)&A[cc * KROW + 104 + 8 * g];
        bf16x8 a2  = *(const bf16x8*)&A[cc * KROW + 64  + 8 * g];
        bf16x8 a3  = *(const bf16x8*)&A[cc * KROW + 96  + 8 * g];
        bf16x8 a4  = *(const bf16x8*)&A[cc * KROW + 128 + 8 * g];

        f32x4 gI = {0,0,0,0}, gF = {0,0,0,0}, gG = {0,0,0,0}, gO = {0,0,0,0};
        gI = __builtin_amdgcn_mfma_f32_16x16x32_bf16(a2, Wf[0][2], gI, 0, 0, 0);
        gF = __builtin_amdgcn_mfma_f32_16x16x32_bf16(a2, Wf[1][2], gF, 0, 0, 0);
        gG = __builtin_amdgcn_mfma_f32_16x16x32_bf16(a2, Wf[2][2], gG, 0, 0, 0);
        gO = __builtin_amdgcn_mfma_f32_16x16x32_bf16(a2, Wf[3][2], gO, 0, 0, 0);
        gI = __builtin_amdgcn_mfma_f32_16x16x32_bf16(a3, Wf[0][3], gI, 0, 0, 0);
        gF = __builtin_amdgcn_mfma_f32_16x16x32_bf16(a3, Wf[1][3], gF, 0, 0, 0);
        gG = __builtin_amdgcn_mfma_f32_16x16x32_bf16(a3, Wf[2][3], gG, 0, 0, 0);
        gO = __builtin_amdgcn_mfma_f32_16x16x32_bf16(a3, Wf[3][3], gO, 0, 0, 0);
        gI = __builtin_amdgcn_mfma_f32_16x16x32_bf16(a4, Wf[0][4], gI, 0, 0, 0);
        gF = __builtin_amdgcn_mfma_f32_16x16x32_bf16(a4, Wf[1][4], gF, 0, 0, 0);
        gG = __builtin_amdgcn_mfma_f32_16x16x32_bf16(a4, Wf[2][4], gG, 0, 0, 0);
        gO = __builtin_amdgcn_mfma_f32_16x16x32_bf16(a4, Wf[3][4], gO, 0, 0, 0);

        if (w < 3) {
            f32x4 p0 = {0,0,0,0};
            p0 = __builtin_amdgcn_mfma_f32_16x16x32_bf16(ah0, Wr0, p0, 0, 0, 0);
            p0 = __builtin_amdgcn_mfma_f32_16x16x32_bf16(ah1, Wr1, p0, 0, 0, 0);
            float lnum = 0.f;
            if (pl) {
                #pragma unroll
                for (int j = 0; j < 4; ++j) {
                    const int row = 4 * g + j;
                    const float xh = p0[j] + brg;
                    const float xm = bf2f((unsigned short)xmr[j]);
                    const uint32_t mb = (uint32_t)(PM[j] >> t) & 1u;
                    lnum += mb ? fabsf(xm - xh) : 0.f;
                    const unsigned short xc16 = mb ? (unsigned short)xmr[j] : f2bf_rne(xh);
                    A[row * KROW + u] = xc16;                               // x_c(t)
                    An[row * KROW + 35 + u] =                               // m(t+1), one step ahead
                        ((PM[j] >> (t + 1)) & 1ull) ? (unsigned short)0x3F80 : (unsigned short)0;
                    stash[row * ROWEL + t * D_ + u] = xc16;                 // imputation archive
                }
            }
            if (lane < 32) lsum[(t * 3 + w) * 32 + lane] = lnum;            // raw partials, no cross-lane
        }
        __syncthreads();   // bar1 (lgkm only): x_c visible

        // ---- post-bar1: x_c-dependent chunks, prefetch, cell update ----
        bf16x8 a0 = *(const bf16x8*)&A[cc * KROW + 0  + 8 * g];
        bf16x8 a1 = *(const bf16x8*)&A[cc * KROW + 32 + 8 * g];
        gI = __builtin_amdgcn_mfma_f32_16x16x32_bf16(a0, Wf[0][0], gI, 0, 0, 0);
        gF = __builtin_amdgcn_mfma_f32_16x16x32_bf16(a0, Wf[1][0], gF, 0, 0, 0);
        gG = __builtin_amdgcn_mfma_f32_16x16x32_bf16(a0, Wf[2][0], gG, 0, 0, 0);
        gO = __builtin_amdgcn_mfma_f32_16x16x32_bf16(a0, Wf[3][0], gO, 0, 0, 0);
        gI = __builtin_amdgcn_mfma_f32_16x16x32_bf16(a1, Wf[0][1], gI, 0, 0, 0);
        gF = __builtin_amdgcn_mfma_f32_16x16x32_bf16(a1, Wf[1][1], gF, 0, 0, 0);
        gG = __builtin_amdgcn_mfma_f32_16x16x32_bf16(a1, Wf[2][1], gG, 0, 0, 0);
        gO = __builtin_amdgcn_mfma_f32_16x16x32_bf16(a1, Wf[3][1], gO, 0, 0, 0);

        if (pl && t + 1 < T_) {          // prefetch next step's m*x (off critical path)
            #pragma unroll
            for (int j = 0; j < 4; ++j)
                xmr[j] = stash[(4 * g + j) * ROWEL + (t + 1) * D_ + u];
        }

        if (g < 2) {
            #pragma unroll
            for (int j = 0; j < 4; ++j) {
                const float iv = rcp_(1.f + exp2_(fmaf(gI[j], -L2E,       bIs)));
                const float fv = rcp_(1.f + exp2_(fmaf(gF[j], -L2E,       bFs)));
                const float gv = fmaf(2.f, rcp_(1.f + exp2_(fmaf(gG[j], -2.f * L2E, bGs))), -1.f);
                const float ov = rcp_(1.f + exp2_(fmaf(gO[j], -L2E,       bOs)));
                const float cn = fmaf(fv, c_reg[j], iv * gv);
                c_reg[j] = cn;
                const float th = fmaf(2.f, rcp_(1.f + exp2_(cn * (-2.f * L2E))), -1.f);
                An[(4 * g + j) * KROW + 72 + u] = (unsigned short)(fbits(ov * th) >> 16);
            }
        }
        __syncthreads();   // bar2 (lgkm only): h(t) visible
    }

    // ---- loss partials: per-t reduce in LDS, spread atomics once per block ----
    if (tid < T_) {
        const int t = tid;
        float num = 0.f;
        for (int i = 0; i < 96; ++i) num += lsum[t * 96 + i];
        float den = 0.f;
        for (int r = 0; r < BT; ++r) den += (float)__popcll(mbits[r * T_ + t]);
        atomicAdd(&ws[t * 8 + (blockIdx.x & 7)], num);
        atomicAdd(&ws[(T_ + t) * 8 + (blockIdx.x & 7)], den);
    }

    // ---- y_h = sigmoid(h_final @ W_out^T + b_out); h(T-1) in Abuf[0] ----
    if (w == 1 && cc < BT) {
        float p = 0.f;
        #pragma unroll
        for (int k = 0; k < 16; ++k)
            p += bf2f(Abuf[0][cc * KROW + 72 + 16 * g + k]) * wout[16 * g + k];
        p += __shfl_xor(p, 16, 64);
        p += __shfl_xor(p, 32, 64);
        if (lane < 16) out[1 + batch0 + cc] = rcp_(1.f + exp2_(-(p + wout[64]) * L2E));
    }

    // ---- bulk dump imputations ----
    for (int i = tid; i < BT * ROWEL; i += 256) {
        const int r = i / ROWEL;
        const int o = i - r * ROWEL;
        out[1 + B_ + (size_t)(batch0 + r) * ROWEL + o] = bf2f(stash[i]);
    }
}

// loss = (1/T) * sum_t num[t] / (den[t] + 1e-5); slots spread 8-way
__global__ void post_kernel(const float* __restrict__ ws, float* __restrict__ out)
{
    const int t = threadIdx.x;  // 64 threads
    float v = 0.f;
    if (t < T_) {
        float num = 0.f, den = 0.f;
        #pragma unroll
        for (int s = 0; s < 8; ++s) {
            num += ws[t * 8 + s];
            den += ws[(T_ + t) * 8 + s];
        }
        v = num / (den + 1e-5f);
    }
    #pragma unroll
    for (int off = 1; off < 64; off <<= 1) v += __shfl_xor(v, off, 64);
    if (t == 0) out[0] = v * (1.0f / T_);
}

extern "C" void kernel_launch(void* const* d_in, const int* in_sizes, int n_in,
                              void* d_out, int out_size, void* d_ws, size_t ws_size,
                              hipStream_t stream) {
    const float* x_t   = (const float*)d_in[0];
    const float* masks = (const float*)d_in[1];
    const float* W_ih  = (const float*)d_in[6];
    const float* W_hh  = (const float*)d_in[7];
    const float* b_ih  = (const float*)d_in[8];
    const float* b_hh  = (const float*)d_in[9];
    const float* W_reg = (const float*)d_in[10];
    const float* b_reg = (const float*)d_in[11];
    const float* W_out = (const float*)d_in[14];
    const float* b_out = (const float*)d_in[15];
    float* out = (float*)d_out;
    float* ws  = (float*)d_ws;

    hipMemsetAsync(ws, 0, 2 * T_ * 8 * sizeof(float), stream);
    brits_main<<<B_ / BT, 256, 0, stream>>>(x_t, masks, W_ih, W_hh, b_ih, b_hh,
                                            W_reg, b_reg, W_out, b_out, ws, out);
    post_kernel<<<1, 64, 0, stream>>>(ws, out);
}

// Round 8
// 99.067 us; speedup vs baseline: 1.0673x; 1.0673x over previous
//
#include <hip/hip_runtime.h>
#include <stdint.h>

#define B_    4096
#define T_    48
#define D_    35
#define TS    40      // stash per-timestep stride (elems)
#define RS    1928    // stash per-row stride (elems) = 48*40 + 8 (bank-skew pad)
#define HS    72      // h-tile row stride (elems)
#define L2E   1.44269504f

typedef float f32x4 __attribute__((ext_vector_type(4)));
typedef short bf16x8 __attribute__((ext_vector_type(8)));

union U4 { uint32_t u[4]; bf16x8 v; };

static __device__ __forceinline__ uint32_t fbits(float x){union{float f;uint32_t u;}v;v.f=x;return v.u;}
static __device__ __forceinline__ float bitsf(uint32_t u){union{uint32_t u;float f;}v;v.u=u;return v.f;}
static __device__ __forceinline__ float bf2f(unsigned short b){return bitsf(((uint32_t)b)<<16);}
static __device__ __forceinline__ unsigned short f2bf_rne(float x){
    uint32_t u=fbits(x); return (unsigned short)((u+0x7fffu+((u>>16)&1u))>>16);
}
static __device__ __forceinline__ float rcp_(float x){return __builtin_amdgcn_rcpf(x);}
static __device__ __forceinline__ float exp2_(float x){return __builtin_amdgcn_exp2f(x);}

#define MFMA __builtin_amdgcn_mfma_f32_16x16x32_bf16

// K-axis permutation (A-frags and gate weights share it; elem i of chunk kc = k-slot kc*32+8g+i):
//   k 0..63   = h            -> W_hh[:,k]
//   k 64..98  = m f0..34     -> W_ih[:,35+f]
//   k 99..101 = x_c f32..34  -> W_ih[:,32+f-32]
//   k 102..127= 0
//   k 128..159= x_c f0..31   -> W_ih[:,f]
// Chunks C0,C1 (h: LDS), C2 (m: regs), pre-epilogue; C3 (m-tail+xc-tail), C4 (xc: shfl-exchange) post.
// x_hat computed TRANSPOSED: mfma(Wreg_tile, h) -> lane(cc,g) holds xhat[f=16nt+4g+j][batch cc],
// so the x_c it produces feeds its own gate A-frags after an intra-wave shfl across g.

__global__ __launch_bounds__(256, 1)
void brits_main(const float* __restrict__ x_t, const float* __restrict__ masks,
                const float* __restrict__ W_ih, const float* __restrict__ W_hh,
                const float* __restrict__ b_ih, const float* __restrict__ b_hh,
                const float* __restrict__ W_reg, const float* __restrict__ b_reg,
                const float* __restrict__ W_out, const float* __restrict__ b_out,
                float* __restrict__ ws, float* __restrict__ out)
{
    __shared__ __align__(16) unsigned short stash[16 * RS];   // 61696 B: bf16(m*x) -> bf16(x_c)
    __shared__ float lsum[T_ * 64];                            // 12288 B
    __shared__ __align__(16) unsigned short hbuf[2][16 * HS];  //  4608 B
    __shared__ unsigned long long mbits[T_ * 16];              //  6144 B: [t][row]
    __shared__ float wout[65];

    const int tid    = threadIdx.x;
    const int lane   = tid & 63;
    const int w      = tid >> 6;
    const int g      = lane >> 4;
    const int cc     = lane & 15;
    const int batch0 = blockIdx.x * 16;
    const int u      = w * 16 + cc;    // gate unit column

    for (int i = tid; i < 1152; i += 256) ((uint32_t*)hbuf)[i] = 0;
    if (tid < 65) wout[tid] = (tid < 64) ? W_out[tid] : b_out[0];

    // stash: bf16(m*x), layout [row][t][TS]
    for (int i = tid; i < 16 * 420; i += 256) {
        const int r = i / 420;
        const int o = (i - r * 420) * 4;
        const float4 xv = *(const float4*)(x_t   + (size_t)(batch0 + r) * 1680 + o);
        const float4 mv = *(const float4*)(masks + (size_t)(batch0 + r) * 1680 + o);
        #pragma unroll
        for (int k2 = 0; k2 < 4; ++k2) {
            const int e = o + k2, tt = e / 35, d = e - 35 * tt;
            stash[r * RS + tt * TS + d] = f2bf_rne((&mv.x)[k2] * (&xv.x)[k2]);
        }
    }
    for (int p = tid; p < 768; p += 256) {
        const int r = p & 15, tt = p >> 4;
        const float* mp = masks + (size_t)(batch0 + r) * 1680 + tt * 35;
        unsigned long long bits = 0;
        for (int d = 0; d < 35; ++d) bits |= (unsigned long long)(mp[d] != 0.f) << d;
        mbits[tt * 16 + r] = bits;
    }

    // ---- gate weights (K-permuted) -> registers ----
    bf16x8 Wf[4][5];
    #pragma unroll
    for (int G = 0; G < 4; ++G) {
        const int n = G * 64 + u;
        #pragma unroll
        for (int kc = 0; kc < 5; ++kc) {
            bf16x8 v;
            #pragma unroll
            for (int i = 0; i < 8; ++i) {
                const int k = kc * 32 + 8 * g + i;
                float f = 0.f;
                if (k < 64)        f = W_hh[n * 64 + k];
                else if (k < 99)   f = W_ih[n * 70 + 35 + (k - 64)];
                else if (k < 102)  f = W_ih[n * 70 + 32 + (k - 99)];
                else if (k >= 128) f = W_ih[n * 70 + (k - 128)];
                v[i] = (short)f2bf_rne(f);
            }
            Wf[G][kc] = v;
        }
    }
    // ---- transposed-x_hat weights: Wrt[nt][kc] = W_reg[16nt+cc][kc*32+8g+i] ----
    bf16x8 Wrt[3][2];
    #pragma unroll
    for (int nt = 0; nt < 3; ++nt) {
        const int row = nt * 16 + cc;
        #pragma unroll
        for (int kc = 0; kc < 2; ++kc) {
            bf16x8 v;
            #pragma unroll
            for (int i = 0; i < 8; ++i)
                v[i] = (short)((row < 35) ? f2bf_rne(W_reg[row * 64 + kc * 32 + 8 * g + i]) : 0);
            Wrt[nt][kc] = v;
        }
    }
    float brg_[12];
    #pragma unroll
    for (int nt = 0; nt < 3; ++nt) {
        #pragma unroll
        for (int j = 0; j < 4; ++j) {
            const int f = 16 * nt + 4 * g + j;
            brg_[nt * 4 + j] = (f < 35) ? b_reg[f] : 0.f;
        }
    }
    const float bIs = -(b_ih[u]       + b_hh[u])       * L2E;
    const float bFs = -(b_ih[64 + u]  + b_hh[64 + u])  * L2E;
    const float bGs = -(b_ih[128 + u] + b_hh[128 + u]) * 2.f * L2E;
    const float bOs = -(b_ih[192 + u] + b_hh[192 + u]) * L2E;
    __syncthreads();

    float c_[4] = {0.f, 0.f, 0.f, 0.f};
    const int srcA = cc + 32 * (g & 1);   // x_c exchange sources (within wave)
    const int srcB = srcA + 16;
    const bool nthi = (g >> 1) != 0;

    #pragma unroll 1
    for (int t = 0; t < T_; ++t) {
        const unsigned short* hc = hbuf[t & 1];
        unsigned short* hn = hbuf[(t + 1) & 1];

        // loads: h frags (shared by gates C0/C1 and transposed P1), mask bits, m*x
        const bf16x8 ah0 = *(const bf16x8*)&hc[cc * HS + 8 * g];
        const bf16x8 ah1 = *(const bf16x8*)&hc[cc * HS + 32 + 8 * g];
        const unsigned long long mb = mbits[t * 16 + cc];
        const int sbase = cc * RS + t * TS;
        const uint2 xm0 = *(const uint2*)&stash[sbase + 4 * g];
        const uint2 xm1 = *(const uint2*)&stash[sbase + 16 + 4 * g];
        const uint2 xm2 = *(const uint2*)&stash[sbase + 32 + 4 * g];

        // C2 m-frag from bitmask
        U4 c2f;
        #pragma unroll
        for (int ii = 0; ii < 4; ++ii) {
            const uint32_t b2 = (uint32_t)(mb >> (8 * g + 2 * ii)) & 3u;
            c2f.u[ii] = ((b2 & 1u) ? 0x3F80u : 0u) | ((b2 & 2u) ? 0x3F800000u : 0u);
        }

        // transposed x_hat: lane(cc,g) gets xhat[16nt+4g+j][batch cc]
        f32x4 p0 = {0,0,0,0}, p1 = {0,0,0,0}, p2 = {0,0,0,0};
        p0 = MFMA(Wrt[0][0], ah0, p0, 0,0,0);
        p1 = MFMA(Wrt[1][0], ah0, p1, 0,0,0);
        p2 = MFMA(Wrt[2][0], ah0, p2, 0,0,0);
        p0 = MFMA(Wrt[0][1], ah1, p0, 0,0,0);
        p1 = MFMA(Wrt[1][1], ah1, p1, 0,0,0);
        p2 = MFMA(Wrt[2][1], ah1, p2, 0,0,0);

        // gates: h + m chunks (independent of this step's x_c)
        f32x4 gI = {0,0,0,0}, gF = {0,0,0,0}, gG = {0,0,0,0}, gO = {0,0,0,0};
        gI = MFMA(ah0, Wf[0][0], gI, 0,0,0);
        gF = MFMA(ah0, Wf[1][0], gF, 0,0,0);
        gG = MFMA(ah0, Wf[2][0], gG, 0,0,0);
        gO = MFMA(ah0, Wf[3][0], gO, 0,0,0);
        gI = MFMA(ah1, Wf[0][1], gI, 0,0,0);
        gF = MFMA(ah1, Wf[1][1], gF, 0,0,0);
        gG = MFMA(ah1, Wf[2][1], gG, 0,0,0);
        gO = MFMA(ah1, Wf[3][1], gO, 0,0,0);
        gI = MFMA(c2f.v, Wf[0][2], gI, 0,0,0);
        gF = MFMA(c2f.v, Wf[1][2], gF, 0,0,0);
        gG = MFMA(c2f.v, Wf[2][2], gG, 0,0,0);
        gO = MFMA(c2f.v, Wf[3][2], gO, 0,0,0);

        // epilogue: x_c (regs), loss partial, packed bf16 pairs
        float lnum = 0.f;
        uint32_t P0a[3], P1a[3];
        #pragma unroll
        for (int nt = 0; nt < 3; ++nt) {
            const f32x4 pp  = (nt == 0) ? p0  : (nt == 1) ? p1  : p2;
            const uint2 xmv = (nt == 0) ? xm0 : (nt == 1) ? xm1 : xm2;
            uint32_t lo = 0, hi = 0;
            #pragma unroll
            for (int j = 0; j < 4; ++j) {
                const int f = 16 * nt + 4 * g + j;
                const float xh = pp[j] + brg_[nt * 4 + j];
                const uint32_t word = (j >> 1) ? xmv.y : xmv.x;
                const uint32_t xm16 = (j & 1) ? (word >> 16) : (word & 0xFFFFu);
                const float xmf = bitsf(xm16 << 16);
                const uint32_t bit = (uint32_t)(mb >> f) & 1u;
                const float xcv = bit ? xmf : xh;
                lnum += bit ? fabsf(xmf - xh) : 0.f;
                const uint32_t tb = fbits(xcv) & 0xFFFF0000u;  // trunc-to-bf16 in hi16
                if (j == 0)      lo  = tb >> 16;
                else if (j == 1) lo |= tb;
                else if (j == 2) hi  = tb >> 16;
                else             hi |= tb;
            }
            P0a[nt] = lo; P1a[nt] = hi;
        }

        // archive x_c + loss partial (wave 0 only; same-value race with other waves' reads is benign)
        if (w == 0) {
            *(uint2*)&stash[sbase + 4 * g]      = make_uint2(P0a[0], P1a[0]);
            *(uint2*)&stash[sbase + 16 + 4 * g] = make_uint2(P0a[1], P1a[1]);
            if (g == 0) *(uint2*)&stash[sbase + 32] = make_uint2(P0a[2], P1a[2]);
            lsum[t * 64 + lane] = lnum;
        }

        // intra-wave exchange: build C4 A-frag = x_c[batch cc][f 8g..8g+7]
        const uint32_t rA0 = __shfl((int)P0a[0], srcA, 64);
        const uint32_t rA1 = __shfl((int)P1a[0], srcA, 64);
        const uint32_t rA2 = __shfl((int)P0a[1], srcA, 64);
        const uint32_t rA3 = __shfl((int)P1a[1], srcA, 64);
        const uint32_t rB0 = __shfl((int)P0a[0], srcB, 64);
        const uint32_t rB1 = __shfl((int)P1a[0], srcB, 64);
        const uint32_t rB2 = __shfl((int)P0a[1], srcB, 64);
        const uint32_t rB3 = __shfl((int)P1a[1], srcB, 64);
        U4 c4f;
        c4f.u[0] = nthi ? rA2 : rA0;
        c4f.u[1] = nthi ? rA3 : rA1;
        c4f.u[2] = nthi ? rB2 : rB0;
        c4f.u[3] = nthi ? rB3 : rB1;

        // C3 frag: [m32,m33 | m34,xc32 | xc33,xc34 | 0] (only g==0 slots carry weight)
        U4 c3f;
        {
            const uint32_t b32 = (uint32_t)(mb >> 32) & 1u;
            const uint32_t b33 = (uint32_t)(mb >> 33) & 1u;
            const uint32_t b34 = (uint32_t)(mb >> 34) & 1u;
            c3f.u[0] = (b32 ? 0x3F80u : 0u) | (b33 ? 0x3F800000u : 0u);
            c3f.u[1] = (b34 ? 0x3F80u : 0u) | (P0a[2] << 16);
            c3f.u[2] = (P0a[2] >> 16) | (P1a[2] << 16);
            c3f.u[3] = 0;
        }

        gI = MFMA(c3f.v, Wf[0][3], gI, 0,0,0);
        gF = MFMA(c3f.v, Wf[1][3], gF, 0,0,0);
        gG = MFMA(c3f.v, Wf[2][3], gG, 0,0,0);
        gO = MFMA(c3f.v, Wf[3][3], gO, 0,0,0);
        gI = MFMA(c4f.v, Wf[0][4], gI, 0,0,0);
        gF = MFMA(c4f.v, Wf[1][4], gF, 0,0,0);
        gG = MFMA(c4f.v, Wf[2][4], gG, 0,0,0);
        gO = MFMA(c4f.v, Wf[3][4], gO, 0,0,0);

        // cell update (rows 4g+j, unit u), write h(t) to other buffer
        #pragma unroll
        for (int j = 0; j < 4; ++j) {
            const float iv = rcp_(1.f + exp2_(fmaf(gI[j], -L2E,       bIs)));
            const float fv = rcp_(1.f + exp2_(fmaf(gF[j], -L2E,       bFs)));
            const float gv = fmaf(2.f, rcp_(1.f + exp2_(fmaf(gG[j], -2.f * L2E, bGs))), -1.f);
            const float ov = rcp_(1.f + exp2_(fmaf(gO[j], -L2E,       bOs)));
            const float cn = fmaf(fv, c_[j], iv * gv);
            c_[j] = cn;
            const float th = fmaf(2.f, rcp_(1.f + exp2_(cn * (-2.f * L2E))), -1.f);
            hn[(4 * g + j) * HS + u] = (unsigned short)(fbits(ov * th) >> 16);
        }
        __syncthreads();   // the single per-step barrier: h(t) visible
    }

    // ---- loss partials: per-t reduce + spread atomics ----
    #pragma unroll 1
    for (int tt = 0; tt < 12; ++tt) {
        const int t = w * 12 + tt;
        float v = lsum[t * 64 + lane];
        v += __shfl_xor(v, 1, 64);  v += __shfl_xor(v, 2, 64);
        v += __shfl_xor(v, 4, 64);  v += __shfl_xor(v, 8, 64);
        v += __shfl_xor(v, 16, 64); v += __shfl_xor(v, 32, 64);
        float den = (lane < 16) ? (float)__popcll(mbits[t * 16 + lane]) : 0.f;
        den += __shfl_xor(den, 1, 64); den += __shfl_xor(den, 2, 64);
        den += __shfl_xor(den, 4, 64); den += __shfl_xor(den, 8, 64);
        if (lane == 0) {
            atomicAdd(&ws[t * 8 + (blockIdx.x & 7)], v);
            atomicAdd(&ws[(T_ + t) * 8 + (blockIdx.x & 7)], den);
        }
    }

    // ---- y_h = sigmoid(h(T-1) @ W_out^T + b_out); h(T-1) in hbuf[0] ----
    if (w == 1) {
        float p = 0.f;
        #pragma unroll
        for (int k = 0; k < 16; ++k)
            p += bf2f(hbuf[0][cc * HS + 16 * g + k]) * wout[16 * g + k];
        p += __shfl_xor(p, 16, 64);
        p += __shfl_xor(p, 32, 64);
        if (lane < 16) out[1 + batch0 + cc] = rcp_(1.f + exp2_(-(p + wout[64]) * L2E));
    }

    // ---- bulk dump imputations ----
    for (int i = tid; i < 16 * 1680; i += 256) {
        const int r = i / 1680;
        const int o = i - r * 1680;
        const int tt = o / 35, d = o - 35 * tt;
        out[1 + B_ + (size_t)(batch0 + r) * 1680 + o] = bf2f(stash[r * RS + tt * TS + d]);
    }
}

// loss = (1/T) * sum_t num[t] / (den[t] + 1e-5); slots spread 8-way
__global__ void post_kernel(const float* __restrict__ ws, float* __restrict__ out)
{
    const int t = threadIdx.x;  // 64 threads
    float v = 0.f;
    if (t < T_) {
        float num = 0.f, den = 0.f;
        #pragma unroll
        for (int s = 0; s < 8; ++s) {
            num += ws[t * 8 + s];
            den += ws[(T_ + t) * 8 + s];
        }
        v = num / (den + 1e-5f);
    }
    #pragma unroll
    for (int off = 1; off < 64; off <<= 1) v += __shfl_xor(v, off, 64);
    if (t == 0) out[0] = v * (1.0f / T_);
}

extern "C" void kernel_launch(void* const* d_in, const int* in_sizes, int n_in,
                              void* d_out, int out_size, void* d_ws, size_t ws_size,
                              hipStream_t stream) {
    const float* x_t   = (const float*)d_in[0];
    const float* masks = (const float*)d_in[1];
    const float* W_ih  = (const float*)d_in[6];
    const float* W_hh  = (const float*)d_in[7];
    const float* b_ih  = (const float*)d_in[8];
    const float* b_hh  = (const float*)d_in[9];
    const float* W_reg = (const float*)d_in[10];
    const float* b_reg = (const float*)d_in[11];
    const float* W_out = (const float*)d_in[14];
    const float* b_out = (const float*)d_in[15];
    float* out = (float*)d_out;
    float* ws  = (float*)d_ws;

    hipMemsetAsync(ws, 0, 2 * T_ * 8 * sizeof(float), stream);
    brits_main<<<B_ / 16, 256, 0, stream>>>(x_t, masks, W_ih, W_hh, b_ih, b_hh,
                                            W_reg, b_reg, W_out, b_out, ws, out);
    post_kernel<<<1, 64, 0, stream>>>(ws, out);
}

// Round 9
// 86.399 us; speedup vs baseline: 1.2238x; 1.1466x over previous
//
#include <hip/hip_runtime.h>
#include <stdint.h>

#define B_    4096
#define T_    48
#define D_    35
#define KROW  168           // A-row stride (elems); MFMA reads k 0..159; 136..167 zero
#define ROWEL (T_ * D_)     // 1680
#define L2E   1.44269504f

typedef float f32x4 __attribute__((ext_vector_type(4)));
typedef short bf16x8 __attribute__((ext_vector_type(8)));

static __device__ __forceinline__ uint32_t fbits(float x){union{float f;uint32_t u;}v;v.f=x;return v.u;}
static __device__ __forceinline__ float bitsf(uint32_t u){union{uint32_t u;float f;}v;v.u=u;return v.f;}
static __device__ __forceinline__ float bf2f(unsigned short b){return bitsf(((uint32_t)b)<<16);}
static __device__ __forceinline__ unsigned short f2bf_rne(float x){
    uint32_t u=fbits(x); return (unsigned short)((u+0x7fffu+((u>>16)&1u))>>16);
}
static __device__ __forceinline__ float rcp_(float x){return __builtin_amdgcn_rcpf(x);}
static __device__ __forceinline__ float exp2_(float x){return __builtin_amdgcn_exp2f(x);}

#define MFMA __builtin_amdgcn_mfma_f32_16x16x32_bf16

// K-axis layout (A tile and weight fragments):
//   k 0..34 = x_c -> W_ih[:,0:35] ; k 35..69 = m -> W_ih[:,35:70]
//   k 70..71 = 0  ; k 72..135 = h -> W_hh   ; k 136..159 = 0
// Wave specialization (8 waves): waves 0..3 = gates (pre-bar kk2..kk4; post-bar
// kk0,kk1 + cell update + h write). Waves 4..6 = P1 + epilogue (x_c, m(t+1)
// pre-write, stash archive, loss). Wave 7 idle in loop.

__global__ __launch_bounds__(512, 1)
void brits_main(const float* __restrict__ x_t, const float* __restrict__ masks,
                const float* __restrict__ W_ih, const float* __restrict__ W_hh,
                const float* __restrict__ b_ih, const float* __restrict__ b_hh,
                const float* __restrict__ W_reg, const float* __restrict__ b_reg,
                const float* __restrict__ W_out, const float* __restrict__ b_out,
                float* __restrict__ ws, float* __restrict__ out)
{
    __shared__ __align__(16) unsigned short Abuf[2][16 * KROW];   // 10752 B
    __shared__ __align__(16) unsigned short stash[16 * ROWEL];    // 53760 B: bf16(m*x) -> bf16(x_c)
    __shared__ unsigned long long mbits[16 * T_];                 //  6144 B: [r][t]
    __shared__ float lsum[T_ * 3 * 64];                           // 36864 B
    __shared__ float wout[65];

    const int tid    = threadIdx.x;
    const int lane   = tid & 63;
    const int w      = tid >> 6;      // wave 0..7
    const int g      = lane >> 4;     // k-subgroup / C row-group
    const int cc     = lane & 15;
    const int batch0 = blockIdx.x * 16;
    const int u      = (w & 3) * 16 + cc;   // gate unit (w<4)
    const int u2     = (w - 4) * 16 + cc;   // x_hat col (w in 4..6)

    // ---- staging (512 threads) ----
    for (int i = tid; i < 16 * KROW; i += 512) ((uint32_t*)Abuf)[i] = 0;  // both buffers
    if (tid < 65) wout[tid] = (tid < 64) ? W_out[tid] : b_out[0];

    for (int i = tid; i < 16 * 210; i += 512) {
        const int r = i / 210;
        const int o = (i - r * 210) * 8;
        const float* xp = x_t   + (size_t)(batch0 + r) * ROWEL + o;
        const float* mp = masks + (size_t)(batch0 + r) * ROWEL + o;
        float xv[8], mv[8];
        *(float4*)&xv[0] = *(const float4*)xp; *(float4*)&xv[4] = *(const float4*)(xp + 4);
        *(float4*)&mv[0] = *(const float4*)mp; *(float4*)&mv[4] = *(const float4*)(mp + 4);
        unsigned short pk[8];
        #pragma unroll
        for (int k = 0; k < 8; ++k) pk[k] = f2bf_rne(mv[k] * xv[k]);
        *(uint4*)&stash[r * ROWEL + o] = *(const uint4*)pk;
    }
    for (int p = tid; p < 16 * T_; p += 512) {
        const int r = p / T_, t = p - r * T_;
        const float* mp = masks + (size_t)(batch0 + r) * ROWEL + t * D_;
        unsigned long long bits = 0;
        for (int d = 0; d < D_; ++d) bits |= (unsigned long long)(mp[d] != 0.f) << d;
        mbits[p] = bits;
    }

    // ---- weights -> registers (per wave group) ----
    bf16x8 Wf[4][5];                 // gate waves only
    float bIs = 0.f, bFs = 0.f, bGs = 0.f, bOs = 0.f;
    if (w < 4) {
        #pragma unroll
        for (int G = 0; G < 4; ++G) {
            const int n = G * 64 + u;
            #pragma unroll
            for (int kc = 0; kc < 5; ++kc) {
                bf16x8 v;
                #pragma unroll
                for (int i = 0; i < 8; ++i) {
                    const int k = kc * 32 + 8 * g + i;
                    float f = 0.f;
                    if (k < 70)                  f = W_ih[n * 70 + k];
                    else if (k >= 72 && k < 136) f = W_hh[n * 64 + (k - 72)];
                    v[i] = (short)f2bf_rne(f);
                }
                Wf[G][kc] = v;
            }
        }
        bIs = -(b_ih[u]       + b_hh[u])       * L2E;
        bFs = -(b_ih[64 + u]  + b_hh[64 + u])  * L2E;
        bGs = -(b_ih[128 + u] + b_hh[128 + u]) * 2.f * L2E;
        bOs = -(b_ih[192 + u] + b_hh[192 + u]) * L2E;
    }
    bf16x8 Wr0 = {0,0,0,0,0,0,0,0}, Wr1 = {0,0,0,0,0,0,0,0};
    float brg = 0.f;
    const bool pw = (w >= 4) && (w < 7);      // P1 waves
    const bool pl = pw && (u2 < 35);          // epilogue-active lanes
    if (pl) {
        #pragma unroll
        for (int i = 0; i < 8; ++i) {
            Wr0[i] = (short)f2bf_rne(W_reg[u2 * 64 + 8 * g + i]);
            Wr1[i] = (short)f2bf_rne(W_reg[u2 * 64 + 32 + 8 * g + i]);
        }
        brg = b_reg[u2];
    }
    __syncthreads();   // stash + mbits ready

    // ---- per-lane mask bitmaps over t, first m*x prefetch, m(0) pre-write ----
    unsigned long long PM[4] = {0, 0, 0, 0};
    uint32_t xmr[4] = {0, 0, 0, 0};
    if (pl) {
        #pragma unroll
        for (int j = 0; j < 4; ++j) {
            const int row = 4 * g + j;
            unsigned long long pm = 0;
            for (int t = 0; t < T_; ++t)
                pm |= ((mbits[row * T_ + t] >> u2) & 1ull) << t;
            PM[j] = pm;
            xmr[j] = stash[row * ROWEL + u2];                      // t=0
            Abuf[0][row * KROW + 35 + u2] = (pm & 1ull) ? (unsigned short)0x3F80 : (unsigned short)0;
        }
    }
    __syncthreads();   // m(0) visible

    float c_[4] = {0.f, 0.f, 0.f, 0.f};

    for (int t = 0; t < T_; ++t) {
        unsigned short* A  = Abuf[t & 1];
        unsigned short* An = Abuf[(t + 1) & 1];

        f32x4 gI = {0,0,0,0}, gF = {0,0,0,0}, gG = {0,0,0,0}, gO = {0,0,0,0};

        if (w < 4) {
            // ---- gate waves pre-bar1: h/m chunks kk2..kk4 ----
            bf16x8 a2 = *(const bf16x8*)&A[cc * KROW + 64  + 8 * g];
            bf16x8 a3 = *(const bf16x8*)&A[cc * KROW + 96  + 8 * g];
            bf16x8 a4 = *(const bf16x8*)&A[cc * KROW + 128 + 8 * g];
            gI = MFMA(a2, Wf[0][2], gI, 0,0,0);
            gF = MFMA(a2, Wf[1][2], gF, 0,0,0);
            gG = MFMA(a2, Wf[2][2], gG, 0,0,0);
            gO = MFMA(a2, Wf[3][2], gO, 0,0,0);
            gI = MFMA(a3, Wf[0][3], gI, 0,0,0);
            gF = MFMA(a3, Wf[1][3], gF, 0,0,0);
            gG = MFMA(a3, Wf[2][3], gG, 0,0,0);
            gO = MFMA(a3, Wf[3][3], gO, 0,0,0);
            gI = MFMA(a4, Wf[0][4], gI, 0,0,0);
            gF = MFMA(a4, Wf[1][4], gF, 0,0,0);
            gG = MFMA(a4, Wf[2][4], gG, 0,0,0);
            gO = MFMA(a4, Wf[3][4], gO, 0,0,0);
        } else if (pw) {
            // ---- P1 waves: x_hat, epilogue, x_c/m/stash/loss ----
            bf16x8 ah0 = *(const bf16x8*)&A[cc * KROW + 72  + 8 * g];
            bf16x8 ah1 = *(const bf16x8*)&A[cc * KROW + 104 + 8 * g];
            f32x4 p0 = {0,0,0,0};
            p0 = MFMA(ah0, Wr0, p0, 0,0,0);
            p0 = MFMA(ah1, Wr1, p0, 0,0,0);
            float lnum = 0.f;
            if (u2 < 35) {
                #pragma unroll
                for (int j = 0; j < 4; ++j) {
                    const int row = 4 * g + j;
                    const float xh = p0[j] + brg;
                    const float xm = bf2f((unsigned short)xmr[j]);
                    const uint32_t mb = (uint32_t)(PM[j] >> t) & 1u;
                    lnum += mb ? fabsf(xm - xh) : 0.f;
                    const unsigned short xc16 = mb ? (unsigned short)xmr[j] : f2bf_rne(xh);
                    A[row * KROW + u2] = xc16;                              // x_c(t)
                    An[row * KROW + 35 + u2] =                              // m(t+1), one step ahead
                        ((PM[j] >> (t + 1)) & 1ull) ? (unsigned short)0x3F80 : (unsigned short)0;
                    stash[row * ROWEL + t * D_ + u2] = xc16;                // imputation archive
                }
            }
            lsum[(t * 3 + (w - 4)) * 64 + lane] = lnum;
        }
        __syncthreads();   // bar1 (lgkm only): x_c visible

        if (w < 4) {
            // ---- gate waves post-bar1: x_c chunks + cell update + h write ----
            bf16x8 a0 = *(const bf16x8*)&A[cc * KROW + 0  + 8 * g];
            bf16x8 a1 = *(const bf16x8*)&A[cc * KROW + 32 + 8 * g];
            gI = MFMA(a0, Wf[0][0], gI, 0,0,0);
            gF = MFMA(a0, Wf[1][0], gF, 0,0,0);
            gG = MFMA(a0, Wf[2][0], gG, 0,0,0);
            gO = MFMA(a0, Wf[3][0], gO, 0,0,0);
            gI = MFMA(a1, Wf[0][1], gI, 0,0,0);
            gF = MFMA(a1, Wf[1][1], gF, 0,0,0);
            gG = MFMA(a1, Wf[2][1], gG, 0,0,0);
            gO = MFMA(a1, Wf[3][1], gO, 0,0,0);
            #pragma unroll
            for (int j = 0; j < 4; ++j) {
                const float iv = rcp_(1.f + exp2_(fmaf(gI[j], -L2E,       bIs)));
                const float fv = rcp_(1.f + exp2_(fmaf(gF[j], -L2E,       bFs)));
                const float gv = fmaf(2.f, rcp_(1.f + exp2_(fmaf(gG[j], -2.f * L2E, bGs))), -1.f);
                const float ov = rcp_(1.f + exp2_(fmaf(gO[j], -L2E,       bOs)));
                const float cn = fmaf(fv, c_[j], iv * gv);
                c_[j] = cn;
                const float th = fmaf(2.f, rcp_(1.f + exp2_(cn * (-2.f * L2E))), -1.f);
                An[(4 * g + j) * KROW + 72 + u] = (unsigned short)(fbits(ov * th) >> 16);
            }
        } else if (pl && t + 1 < T_) {
            #pragma unroll
            for (int j = 0; j < 4; ++j)                  // prefetch next step's m*x
                xmr[j] = stash[(4 * g + j) * ROWEL + (t + 1) * D_ + u2];
        }
        __syncthreads();   // bar2 (lgkm only): h(t) visible
    }

    // ---- loss partials: per-t reduce + spread atomics (once per block) ----
    if (tid < T_) {
        const int t = tid;
        float num = 0.f;
        for (int i = 0; i < 192; ++i) num += lsum[t * 192 + i];
        float den = 0.f;
        for (int r = 0; r < 16; ++r) den += (float)__popcll(mbits[r * T_ + t]);
        atomicAdd(&ws[t * 8 + (blockIdx.x & 7)], num);
        atomicAdd(&ws[(T_ + t) * 8 + (blockIdx.x & 7)], den);
    }

    // ---- y_h = sigmoid(h(T-1) @ W_out^T + b_out); h(T-1) in Abuf[0] ----
    if (w == 1) {
        float p = 0.f;
        #pragma unroll
        for (int k = 0; k < 16; ++k)
            p += bf2f(Abuf[0][cc * KROW + 72 + 16 * g + k]) * wout[16 * g + k];
        p += __shfl_xor(p, 16, 64);
        p += __shfl_xor(p, 32, 64);
        if (lane < 16) out[1 + batch0 + cc] = rcp_(1.f + exp2_(-(p + wout[64]) * L2E));
    }

    // ---- bulk dump imputations ----
    for (int i = tid; i < 16 * ROWEL; i += 512) {
        const int r = i / ROWEL;
        const int o = i - r * ROWEL;
        out[1 + B_ + (size_t)(batch0 + r) * ROWEL + o] = bf2f(stash[i]);
    }
}

// loss = (1/T) * sum_t num[t] / (den[t] + 1e-5); slots spread 8-way
__global__ void post_kernel(const float* __restrict__ ws, float* __restrict__ out)
{
    const int t = threadIdx.x;  // 64 threads
    float v = 0.f;
    if (t < T_) {
        float num = 0.f, den = 0.f;
        #pragma unroll
        for (int s = 0; s < 8; ++s) {
            num += ws[t * 8 + s];
            den += ws[(T_ + t) * 8 + s];
        }
        v = num / (den + 1e-5f);
    }
    #pragma unroll
    for (int off = 1; off < 64; off <<= 1) v += __shfl_xor(v, off, 64);
    if (t == 0) out[0] = v * (1.0f / T_);
}

extern "C" void kernel_launch(void* const* d_in, const int* in_sizes, int n_in,
                              void* d_out, int out_size, void* d_ws, size_t ws_size,
                              hipStream_t stream) {
    const float* x_t   = (const float*)d_in[0];
    const float* masks = (const float*)d_in[1];
    const float* W_ih  = (const float*)d_in[6];
    const float* W_hh  = (const float*)d_in[7];
    const float* b_ih  = (const float*)d_in[8];
    const float* b_hh  = (const float*)d_in[9];
    const float* W_reg = (const float*)d_in[10];
    const float* b_reg = (const float*)d_in[11];
    const float* W_out = (const float*)d_in[14];
    const float* b_out = (const float*)d_in[15];
    float* out = (float*)d_out;
    float* ws  = (float*)d_ws;

    hipMemsetAsync(ws, 0, 2 * T_ * 8 * sizeof(float), stream);
    brits_main<<<B_ / 16, 512, 0, stream>>>(x_t, masks, W_ih, W_hh, b_ih, b_hh,
                                            W_reg, b_reg, W_out, b_out, ws, out);
    post_kernel<<<1, 64, 0, stream>>>(ws, out);
}